// Round 7
// baseline (159.103 us; speedup 1.0000x reference)
//
#include <hip/hip_runtime.h>
#include <hip/hip_bf16.h>
#include <math.h>

// DscaGRUCell rev 7 — uniform bf16 GEMM path (inputs pre-converted in fused
// prep), 4-buffer depth-3 pipeline with uniform counted vmcnt(6) (loads aged
// 3 steps), clamped tail prefetch keeps per-step vmem counts constant.
// T1 XCD-chunked swizzle retained.

#define TAU_F 0.5f

typedef __bf16 bf16x8 __attribute__((ext_vector_type(8)));
typedef __bf16 bf16x4 __attribute__((ext_vector_type(4)));
typedef float f32x4 __attribute__((ext_vector_type(4)));

__device__ __forceinline__ void gload16(const void* g, void* l) {
    __builtin_amdgcn_global_load_lds(
        (const __attribute__((address_space(1))) void*)g,
        (__attribute__((address_space(3))) void*)l, 16, 0, 0);
}

struct SubGemm {
    const __bf16* A;  // M x lda row-major bf16 (zero-padded in K where needed)
    int lda;
    const __bf16* BT; // N x Kpad row-major (pre-transposed, zero-padded bf16)
    int ldbt;
    float* C;         // fp32 (partial) out
    int ldc;
    long long strideC;
    int Ksub;         // K per split slice (mult of 32)
    int nbx;          // col tiles (N/128)
    int pairSplit;    // col tiles >= this use A + pairAOff
    int pairAOff;     // element offset
};

// 64x128 tile, BK=32, 4 waves (each 2x4 frags of 16x16x32 bf16 MFMA).
// Schedule: 4 LDS bufs, prefetch depth 3, 3 vmem ops/wave/slot.
//   prologue: issue slots 0,1,2 (9 ops)
//   step t: wait vmcnt(6) [slot t done; slots t+1,t+2 in flight], lgkmcnt(0),
//           s_barrier; ds_read buf t&3; issue slot t+3 (k clamped at tail so
//           counts stay uniform; dest buf (t+3)&3 was consumed at step t-1);
//           16.. 8 MFMAs.
__global__ __launch_bounds__(256) void gemm_dual(SubGemm g1, SubGemm g2, int blocks1)
{
    __shared__ __bf16 As[4][64][32];
    __shared__ __bf16 Bs[4][128][32];

    const int tid = threadIdx.x, w = tid >> 6, l = tid & 63;

    // T1: XCD-chunked swizzle (nwg always % 8 == 0 here)
    const int gx = gridDim.x;
    const int nwg = gx * (int)gridDim.y;
    const int hw = (int)blockIdx.y * gx + (int)blockIdx.x;
    const int lg = (hw & 7) * (nwg >> 3) + (hw >> 3);
    const int bxl_lin = lg % gx;
    const int by = lg / gx;

    const bool second = bxl_lin >= blocks1;
    const SubGemm& g = second ? g2 : g1;
    const int bxl = second ? bxl_lin - blocks1 : bxl_lin;
    const int ct = bxl % g.nbx, spl = bxl / g.nbx;
    const int brow = by * 64, bcol = ct * 128;
    const int k_begin = spl * g.Ksub;
    const int nt = g.Ksub >> 5;
    float* C = g.C + (size_t)spl * g.strideC;
    const int aoff = (ct >= g.pairSplit) ? g.pairAOff : 0;

    // staging geometry (lane covers (row, 16B segment)); LDS dest is
    // wave-uniform base + lane*16 per global_load_lds semantics.
    const int sar = w * 16 + (l >> 2);
    const int sbr = w * 32 + (l >> 2);
    const int seg = (l & 3) * 8;

    const __bf16* Ar  = g.A + aoff + (size_t)(brow + sar) * g.lda + seg + k_begin;
    const __bf16* Bg0 = g.BT + (size_t)(bcol + sbr) * g.ldbt + seg + k_begin;
    const __bf16* Bg1 = Bg0 + (size_t)16 * g.ldbt;

    f32x4 acc[2][4] = {};
    const int fr = l & 15, fk = (l >> 4) * 8;
    const int wr = (w >> 1) * 32, wc = (w & 1) * 64;
    const int kmax = (nt - 1) * 32;

#define ISSUE(slot)                                                        \
    {                                                                      \
        const int _s = (slot);                                             \
        const int _k = (_s * 32 < kmax) ? _s * 32 : kmax;                  \
        const int _b = _s & 3;                                             \
        gload16(Ar + _k,  &As[_b][w * 16][0]);                             \
        gload16(Bg0 + _k, &Bs[_b][w * 32][0]);                             \
        gload16(Bg1 + _k, &Bs[_b][w * 32 + 16][0]);                        \
    }

    ISSUE(0) ISSUE(1) ISSUE(2)

    for (int t = 0; t < nt; ++t) {
        asm volatile("s_waitcnt vmcnt(6)" ::: "memory");
        asm volatile("s_waitcnt lgkmcnt(0)" ::: "memory");
        __builtin_amdgcn_s_barrier();

        const int bi = t & 3;
        bf16x8 a[2], b[4];
#pragma unroll
        for (int m = 0; m < 2; ++m) a[m] = *(const bf16x8*)&As[bi][wr + m * 16 + fr][fk];
#pragma unroll
        for (int n = 0; n < 4; ++n) b[n] = *(const bf16x8*)&Bs[bi][wc + n * 16 + fr][fk];

        ISSUE(t + 3)

#pragma unroll
        for (int m = 0; m < 2; ++m)
#pragma unroll
            for (int n = 0; n < 4; ++n)
                acc[m][n] = __builtin_amdgcn_mfma_f32_16x16x32_bf16(a[m], b[n], acc[m][n], 0, 0, 0);
    }
#undef ISSUE

    // epilogue: raw fp32 store. C/D: col=lane&15, row=(lane>>4)*4+reg
    const int fq = (l >> 4) * 4;
#pragma unroll
    for (int m = 0; m < 2; ++m)
#pragma unroll
        for (int n = 0; n < 4; ++n)
#pragma unroll
            for (int r = 0; r < 4; ++r) {
                int row = brow + wr + m * 16 + fq + r;
                int col = bcol + wc + n * 16 + fr;
                C[(size_t)row * g.ldc + col] = acc[m][n][r];
            }
}

// ---------------- prep: inputs->bf16 Xb, crohis->bf16, all weight transposes -
__global__ __launch_bounds__(256) void prep_all(
    const float* __restrict__ inputs, const float* __restrict__ crohis,
    const float* __restrict__ ew1, const float* __restrict__ ew2,
    const float* __restrict__ w12, const float* __restrict__ u12,
    const float* __restrict__ v12, const float* __restrict__ w21,
    const float* __restrict__ u21, const float* __restrict__ v21,
    const float* __restrict__ cd_w, const float* __restrict__ cw_w,
    const float* __restrict__ kern, const float* __restrict__ rkern,
    __bf16* __restrict__ Xb, __bf16* __restrict__ crohis_bf,
    __bf16* __restrict__ WT, __bf16* __restrict__ WcatT,
    __bf16* __restrict__ cdT, __bf16* __restrict__ cwT,
    __bf16* __restrict__ kernT, __bf16* __restrict__ rkernT)
{
    int i = blockIdx.x * 256 + threadIdx.x;
    if (i < 1024000) {                      // Xb <- X1 (cols 0..1999)
        int r = i / 250, c = (i - r * 250) * 8;
        const float* p = inputs + (size_t)r * 4000 + c;
        f32x4 v0 = *(const f32x4*)p, v1 = *(const f32x4*)(p + 4);
        __bf16 o[8];
#pragma unroll
        for (int z = 0; z < 4; ++z) { o[z] = (__bf16)v0[z]; o[4 + z] = (__bf16)v1[z]; }
        *(bf16x8*)(Xb + (size_t)r * 4096 + c) = *(bf16x8*)o;
        return;
    }
    i -= 1024000;
    if (i < 1024000) {                      // Xb <- X2 (out cols 2048..4047)
        int r = i / 250, c = (i - r * 250) * 8;
        const float* p = inputs + (size_t)r * 4000 + 2000 + c;
        f32x4 v0 = *(const f32x4*)p, v1 = *(const f32x4*)(p + 4);
        __bf16 o[8];
#pragma unroll
        for (int z = 0; z < 4; ++z) { o[z] = (__bf16)v0[z]; o[4 + z] = (__bf16)v1[z]; }
        *(bf16x8*)(Xb + (size_t)r * 4096 + 2048 + c) = *(bf16x8*)o;
        return;
    }
    i -= 1024000;
    if (i < 49152) {                        // Xb zero pads (cols 2000-2047, 4048-4095)
        int r = i / 12, gg = i - r * 12;
        int c = (gg < 6) ? 2000 + gg * 8 : 4048 + (gg - 6) * 8;
        __bf16 o[8] = {};
        *(bf16x8*)(Xb + (size_t)r * 4096 + c) = *(bf16x8*)o;
        return;
    }
    i -= 49152;
    if (i < 262144) {                       // crohis -> bf16
        int e = i * 8;
        const float* p = crohis + e;
        f32x4 v0 = *(const f32x4*)p, v1 = *(const f32x4*)(p + 4);
        __bf16 o[8];
#pragma unroll
        for (int z = 0; z < 4; ++z) { o[z] = (__bf16)v0[z]; o[4 + z] = (__bf16)v1[z]; }
        *(bf16x8*)(crohis_bf + e) = *(bf16x8*)o;
        return;
    }
    i -= 262144;
    if (i < 131072) {                       // WT: 512 x 2048
        int e = i * 8, n = e >> 11, k0 = e & 2047;
        __bf16 o[8];
#pragma unroll
        for (int z = 0; z < 8; ++z) {
            int k = k0 + z;
            float v = 0.f;
            if (k < 2000) v = (n < 256) ? ew1[(size_t)k * 256 + n]
                                        : ew2[(size_t)k * 256 + (n - 256)];
            o[z] = (__bf16)v;
        }
        *(bf16x8*)(WT + e) = *(bf16x8*)o;
        return;
    }
    i -= 131072;
    if (i < 65536) {                        // WcatT: 1024 x 512
        int e = i * 8, n = e >> 9, k0 = e & 511;
        int jm = n & 255;
        __bf16 o[8];
#pragma unroll
        for (int z = 0; z < 8; ++z) {
            int k = k0 + z; bool khi = k >= 256; int kk = k & 255;
            float v;
            if (n < 256)      v = khi ? u12[kk * 256 + jm] : w12[kk * 256 + jm];
            else if (n < 512) v = khi ? w21[kk * 256 + jm] : u21[kk * 256 + jm];
            else if (n < 768) v = khi ? v12[kk * 256 + jm] : 0.f;
            else              v = khi ? 0.f : v21[kk * 256 + jm];
            o[z] = (__bf16)v;
        }
        *(bf16x8*)(WcatT + e) = *(bf16x8*)o;
        return;
    }
    i -= 65536;
    if (i < 32768) {                        // cdT
        int e = i * 8, n = e >> 9, k0 = e & 511;
        __bf16 o[8];
#pragma unroll
        for (int z = 0; z < 8; ++z) o[z] = (__bf16)cd_w[(size_t)(k0 + z) * 512 + n];
        *(bf16x8*)(cdT + e) = *(bf16x8*)o;
        return;
    }
    i -= 32768;
    if (i < 32768) {                        // cwT
        int e = i * 8, n = e >> 9, k0 = e & 511;
        __bf16 o[8];
#pragma unroll
        for (int z = 0; z < 8; ++z) o[z] = (__bf16)cw_w[(size_t)(k0 + z) * 512 + n];
        *(bf16x8*)(cwT + e) = *(bf16x8*)o;
        return;
    }
    i -= 32768;
    if (i < 98304) {                        // kernT: 1536 x 512
        int e = i * 8, n = e >> 9, k0 = e & 511;
        __bf16 o[8];
#pragma unroll
        for (int z = 0; z < 8; ++z) o[z] = (__bf16)kern[(size_t)(k0 + z) * 1536 + n];
        *(bf16x8*)(kernT + e) = *(bf16x8*)o;
        return;
    }
    i -= 98304;
    if (i < 98304) {                        // rkernT: 1536 x 512
        int e = i * 8, n = e >> 9, k0 = e & 511;
        __bf16 o[8];
#pragma unroll
        for (int z = 0; z < 8; ++z) o[z] = (__bf16)rkern[(size_t)(k0 + z) * 1536 + n];
        *(bf16x8*)(rkernT + e) = *(bf16x8*)o;
    }
}

// ---------------- R-A: E = bf16(sum P12), cro = bf16(tanh(P4 + cd_b)) -------
__global__ __launch_bounds__(256) void reduce_A(
    const float* __restrict__ P12, const float* __restrict__ P4,
    const float* __restrict__ cd_b,
    __bf16* __restrict__ E, __bf16* __restrict__ cro)
{
    int b = blockIdx.x;
    int i = (((b & 2047) * 256) + threadIdx.x) * 4;
    if (b < 2048) {
        f32x4 p0 = *(const f32x4*)(P12 + i);
        f32x4 p1 = *(const f32x4*)(P12 + (1 << 21) + i);
        __bf16 o[4];
#pragma unroll
        for (int j = 0; j < 4; ++j) o[j] = (__bf16)(p0[j] + p1[j]);
        *(bf16x4*)&E[i] = *(bf16x4*)o;
    } else {
        f32x4 p0 = *(const f32x4*)(P4 + i);
        int c = i & 511;
        __bf16 o[4];
#pragma unroll
        for (int j = 0; j < 4; ++j) o[j] = (__bf16)tanhf(p0[j] + cd_b[c + j]);
        *(bf16x4*)&cro[i] = *(bf16x4*)o;
    }
}

// ---------------- fuse1: attention softmax + x + crohis_new, and hprev ------
__global__ __launch_bounds__(256) void fuse1(
    const float* __restrict__ T, const __bf16* __restrict__ E,
    const float* __restrict__ crohis,
    const float* __restrict__ P5,
    const float* __restrict__ h_tm1, const float* __restrict__ cw_b,
    __bf16* __restrict__ x, float* __restrict__ cro_out,
    float* __restrict__ hprev, __bf16* __restrict__ hprev_bf)
{
    __shared__ float s4[4];
    int b = blockIdx.x;
    int j = threadIdx.x;
    if (b < 4096) {
        const float* t = T + (size_t)b * 1024;
        float s12 = tanhf(t[j])       * t[512 + j];
        float s21 = tanhf(t[256 + j]) * t[768 + j];
        float v = s12;
#pragma unroll
        for (int o = 32; o >= 1; o >>= 1) v = fmaxf(v, __shfl_xor(v, o, 64));
        __syncthreads(); if ((j & 63) == 0) s4[j >> 6] = v; __syncthreads();
        float m12 = fmaxf(fmaxf(s4[0], s4[1]), fmaxf(s4[2], s4[3]));
        float e12 = expf(s12 - m12);
        v = e12;
#pragma unroll
        for (int o = 32; o >= 1; o >>= 1) v += __shfl_xor(v, o, 64);
        __syncthreads(); if ((j & 63) == 0) s4[j >> 6] = v; __syncthreads();
        float sum12 = s4[0] + s4[1] + s4[2] + s4[3];
        v = s21;
#pragma unroll
        for (int o = 32; o >= 1; o >>= 1) v = fmaxf(v, __shfl_xor(v, o, 64));
        __syncthreads(); if ((j & 63) == 0) s4[j >> 6] = v; __syncthreads();
        float m21 = fmaxf(fmaxf(s4[0], s4[1]), fmaxf(s4[2], s4[3]));
        float e21 = expf(s21 - m21);
        v = e21;
#pragma unroll
        for (int o = 32; o >= 1; o >>= 1) v += __shfl_xor(v, o, 64);
        __syncthreads(); if ((j & 63) == 0) s4[j >> 6] = v; __syncthreads();
        float sum21 = s4[0] + s4[1] + s4[2] + s4[3];

        size_t b0 = (size_t)b * 512 + j, b1 = b0 + 256;
        float x1 = (float)E[b0] * (e12 / sum12);
        float x2 = (float)E[b1] * (e21 / sum21);
        x[b0] = (__bf16)x1;
        x[b1] = (__bf16)x2;
        cro_out[b0] = TAU_F * crohis[b0] + (1.f - TAU_F) * x1;
        cro_out[b1] = TAU_F * crohis[b1] + (1.f - TAU_F) * x2;
    } else {
        int i = ((b - 4096) * 256 + j) * 4;
        f32x4 p = *(const f32x4*)(P5 + i);
        f32x4 ht = *(const f32x4*)(h_tm1 + i);
        int c = i & 511;
        f32x4 o; __bf16 ob[4];
#pragma unroll
        for (int q = 0; q < 4; ++q) {
            float hv = ht[q] + tanhf(p[q] + cw_b[c + q]);
            o[q] = hv; ob[q] = (__bf16)hv;
        }
        *(f32x4*)(hprev + i) = o;
        *(bf16x4*)&hprev_bf[i] = *(bf16x4*)ob;
    }
}

// ---------------- gates: rh = sigmoid(mx_r + bias_r + mi_r) * hprev ----------
__global__ __launch_bounds__(256) void gates_k(
    const float* __restrict__ mx, const float* __restrict__ mi2,
    const float* __restrict__ hprev, const float* __restrict__ bias,
    __bf16* __restrict__ rh)
{
    int i = (blockIdx.x * 256 + threadIdx.x) * 4;
    int row = i >> 9, c = i & 511;
    f32x4 a  = *(const f32x4*)(mx + (size_t)row * 1536 + 512 + c);
    f32x4 m  = *(const f32x4*)(mi2 + (size_t)row * 1024 + 512 + c);
    f32x4 hp = *(const f32x4*)(hprev + i);
    f32x4 bb = *(const f32x4*)(bias + 512 + c);
    __bf16 o[4];
#pragma unroll
    for (int q = 0; q < 4; ++q) {
        float r = 1.f / (1.f + expf(-(a[q] + bb[q] + m[q])));
        o[q] = (__bf16)(r * hp[q]);
    }
    *(bf16x4*)&rh[i] = *(bf16x4*)o;
}

// ---------------- final: h ---------------------------------------------------
__global__ __launch_bounds__(256) void final_k(
    const float* __restrict__ mx, const float* __restrict__ mi2,
    const float* __restrict__ P8a, const float* __restrict__ P8b,
    const float* __restrict__ hprev, const float* __restrict__ bias,
    float* __restrict__ h)
{
    int i = (blockIdx.x * 256 + threadIdx.x) * 4;
    int row = i >> 9, c = i & 511;
    f32x4 xz = *(const f32x4*)(mx + (size_t)row * 1536 + c);
    f32x4 xh = *(const f32x4*)(mx + (size_t)row * 1536 + 1024 + c);
    f32x4 mz = *(const f32x4*)(mi2 + (size_t)row * 1024 + c);
    f32x4 p0 = *(const f32x4*)(P8a + i);
    f32x4 p1 = *(const f32x4*)(P8b + i);
    f32x4 hp = *(const f32x4*)(hprev + i);
    f32x4 bz = *(const f32x4*)(bias + c);
    f32x4 bh = *(const f32x4*)(bias + 1024 + c);
    f32x4 o;
#pragma unroll
    for (int q = 0; q < 4; ++q) {
        float z = 1.f / (1.f + expf(-(xz[q] + bz[q] + mz[q])));
        float hh = tanhf(xh[q] + bh[q] + p0[q] + p1[q]);
        o[q] = z * hp[q] + (1.f - z) * hh;
    }
    *(f32x4*)(h + i) = o;
}

// ---------------- launch -----------------------------------------------------
extern "C" void kernel_launch(void* const* d_in, const int* in_sizes, int n_in,
                              void* d_out, int out_size, void* d_ws, size_t ws_size,
                              hipStream_t stream)
{
    (void)in_sizes; (void)n_in; (void)out_size; (void)ws_size;

    const float* inputs = (const float*)d_in[0];
    const float* h_tm1  = (const float*)d_in[1];
    const float* crohis = (const float*)d_in[2];
    const float* ew1    = (const float*)d_in[3];
    const float* ew2    = (const float*)d_in[4];
    const float* ca12w  = (const float*)d_in[5];
    const float* ca12u  = (const float*)d_in[6];
    const float* ca12v  = (const float*)d_in[7];
    const float* ca21w  = (const float*)d_in[8];
    const float* ca21u  = (const float*)d_in[9];
    const float* ca21v  = (const float*)d_in[10];
    const float* cw_w   = (const float*)d_in[11];
    const float* cw_b   = (const float*)d_in[12];
    const float* cd_w   = (const float*)d_in[13];
    const float* cd_b   = (const float*)d_in[14];
    const float* kern   = (const float*)d_in[15];
    const float* rkern  = (const float*)d_in[16];
    const float* bias   = (const float*)d_in[17];

    char* ws = (char*)d_ws;
    const size_t MB = 1 << 20;
    // lifetimes annotated; all aliases verified phase-disjoint.
    float*  P12       = (float*)(ws + 0);          // 16MB [A]
    float*  P4        = (float*)(ws + 16 * MB);    // 8MB  [A]
    __bf16* Xb        = (__bf16*)(ws + 24 * MB);   // 32MB [prep..A]
    __bf16* crohis_bf = (__bf16*)(ws + 56 * MB);   // 4MB  [prep..A]
    __bf16* E         = (__bf16*)(ws + 32 * MB);   // 4MB  [redA..fuse1] (over Xb)
    __bf16* cro_bf    = (__bf16*)(ws + 36 * MB);   // 4MB  [redA..B]     (over Xb)
    float*  T         = (float*)(ws + 0);          // 16MB [B..fuse1]
    float*  P5        = (float*)(ws + 16 * MB);    // 8MB  [B..fuse1]
    __bf16* x         = (__bf16*)(ws + 40 * MB);   // 4MB  [fuse1..C]    (over Xb)
    float*  hprev     = (float*)(ws + 24 * MB);    // 8MB  [fuse1..final](over Xb)
    __bf16* hprev_bf  = (__bf16*)(ws + 64 * MB);   // 4MB  [fuse1..C]
    float*  mx        = (float*)(ws + 0);          // 24MB [C..final]
    float*  mi2       = (float*)(ws + 44 * MB);    // 16MB [C..final]
    __bf16* rh        = (__bf16*)(ws + 32 * MB);   // 4MB  [gates..G8] (over E)
    float*  P8        = (float*)(ws + 36 * MB);    // s0 @36-44 (over cro_bf/x)
    float*  P8b       = (float*)(ws + 60 * MB);    // s1 @60-68 (over hprev_bf)
    __bf16* WT        = (__bf16*)(ws + 68 * MB);   // 2MB
    __bf16* WcatT     = (__bf16*)(ws + 70 * MB);   // 1MB
    __bf16* cdT       = (__bf16*)(ws + 71 * MB);   // 0.5MB
    __bf16* cwT       = (__bf16*)(ws + 71 * MB + 512 * 1024);
    __bf16* kernT     = (__bf16*)(ws + 72 * MB);   // 1.5MB
    __bf16* rkernT    = (__bf16*)(ws + 73 * MB + 512 * 1024);  // ends 75MB

    float* h_out   = (float*)d_out;
    float* cro_out = (float*)d_out + 2 * 1048576;

    const int BIG = 1 << 30;

    // prep: 2,818,048 threads = 11008 blocks
    prep_all<<<11008, 256, 0, stream>>>(inputs, crohis, ew1, ew2,
                                        ca12w, ca12u, ca12v, ca21w, ca21u, ca21v,
                                        cd_w, cw_w, kern, rkern,
                                        Xb, crohis_bf, WT, WcatT, cdT, cwT,
                                        kernT, rkernT);

    // Phase A: G12 (split-K=2) + G4          [nwg=768]
    SubGemm gA1 = { Xb,        4096, WT,  2048, P12, 512, 1ll << 21, 1024, 4, 2, 2048 };
    SubGemm gA2 = { crohis_bf,  512, cdT,  512, P4,  512, 0,          512, 4, BIG, 0 };
    gemm_dual<<<dim3(12, 64), 256, 0, stream>>>(gA1, gA2, 8);

    reduce_A<<<4096, 256, 0, stream>>>(P12, P4, cd_b, E, cro_bf);

    // Phase B: G3 + G5                        [nwg=768]
    SubGemm gB1 = { E,      512, WcatT, 512, T,  1024, 0, 512, 8, BIG, 0 };
    SubGemm gB2 = { cro_bf, 512, cwT,   512, P5, 512,  0, 512, 4, BIG, 0 };
    gemm_dual<<<dim3(12, 64), 256, 0, stream>>>(gB1, gB2, 8);

    fuse1<<<6144, 256, 0, stream>>>(T, E, crohis, P5, h_tm1, cw_b,
                                    x, cro_out, hprev, hprev_bf);

    // Phase C: G6 (mx) + G7 (mi2)             [nwg=1280]
    SubGemm gC1 = { x,        512, kernT,  512, mx,  1536, 0, 512, 12, BIG, 0 };
    SubGemm gC2 = { hprev_bf, 512, rkernT, 512, mi2, 1024, 0, 512, 8,  BIG, 0 };
    gemm_dual<<<dim3(20, 64), 256, 0, stream>>>(gC1, gC2, 12);

    gates_k<<<2048, 256, 0, stream>>>(mx, mi2, hprev, bias, rh);

    // G8: split-K=2 (slices @36MB, @60MB; stride 6M elems)  [nwg=512]
    SubGemm gG = { rh, 512, rkernT + (size_t)1024 * 512, 512, P8, 512, 6ll << 20, 256, 4, BIG, 0 };
    gemm_dual<<<dim3(8, 64), 256, 0, stream>>>(gG, gG, 8);

    final_k<<<2048, 256, 0, stream>>>(mx, mi2, P8, P8b, hprev, bias, h_out);
}

// Round 8
// 134.485 us; speedup vs baseline: 1.1831x; 1.1831x over previous
//
#include <hip/hip_runtime.h>
#include <hip/hip_bf16.h>
#include <math.h>

// DscaGRUCell rev 8 — fused fp32-A GEMM path with FIXED 2-step-aged vmcnt
// schedule (4 reg sets, unroll-4), LDS-tiled weight transpose prep (no input
// pre-conversion pass). bf16 phases keep rev7's 4-buf depth-3 vmcnt(6) loop.
// T1 XCD-chunked swizzle retained.

#define TAU_F 0.5f

typedef __bf16 bf16x8 __attribute__((ext_vector_type(8)));
typedef __bf16 bf16x4 __attribute__((ext_vector_type(4)));
typedef float f32x4 __attribute__((ext_vector_type(4)));

__device__ __forceinline__ void gload16(const void* g, void* l) {
    __builtin_amdgcn_global_load_lds(
        (const __attribute__((address_space(1))) void*)g,
        (__attribute__((address_space(3))) void*)l, 16, 0, 0);
}

struct SubGemm {
    const void* A;    // M x lda (f32 if AFP32 else bf16)
    int lda;
    int Kvalid;       // valid A cols (AFP32: loads clamp; BT zero-padded beyond)
    const __bf16* BT; // N x Kpad row-major (pre-transposed, zero-padded bf16)
    int ldbt;
    float* C;         // fp32 (partial) out
    int ldc;
    long long strideC;
    int Ksub;         // K per split slice (mult of 32; AFP32: mult of 128)
    int nbx;          // col tiles (N/128)
    int pairSplit;    // col tiles >= this use A + pairAOff
    int pairAOff;     // element offset
};

// 64x128 tile, BK=32, 4 waves (each 2x4 frags of 16x16x32 bf16 MFMA).
// bf16 path: 4 LDS bufs, depth 3, 3 gload_lds/step, wait vmcnt(6).
// AFP32 path: A reg-staged (f32x4 x2 -> cvt -> ds_write), 4 reg sets, unroll-4;
//   per step: wait vmcnt(4) [A-regs(t+1) & B(t), both aged 2 steps], lgkm(0),
//   barrier, ds_read frags(t), ds_write A(t+1), issue Aregs(t+3) + B(t+2).
template <bool AFP32>
__global__ __launch_bounds__(256) void gemm_dual(SubGemm g1, SubGemm g2, int blocks1)
{
    __shared__ __bf16 As[4][64][32];
    __shared__ __bf16 Bs[4][128][32];

    const int tid = threadIdx.x, w = tid >> 6, l = tid & 63;

    // T1: XCD-chunked swizzle (nwg always % 8 == 0 here)
    const int gx = gridDim.x;
    const int nwg = gx * (int)gridDim.y;
    const int hw = (int)blockIdx.y * gx + (int)blockIdx.x;
    const int lg = (hw & 7) * (nwg >> 3) + (hw >> 3);
    const int bxl_lin = lg % gx;
    const int by = lg / gx;

    const bool second = bxl_lin >= blocks1;
    const SubGemm& g = second ? g2 : g1;
    const int bxl = second ? bxl_lin - blocks1 : bxl_lin;
    const int ct = bxl % g.nbx, spl = bxl / g.nbx;
    const int brow = by * 64, bcol = ct * 128;
    const int k_begin = spl * g.Ksub;
    const int nt = g.Ksub >> 5;
    float* C = g.C + (size_t)spl * g.strideC;
    const int aoff = (ct >= g.pairSplit) ? g.pairAOff : 0;

    const int sar = w * 16 + (l >> 2);
    const int sbr = w * 32 + (l >> 2);
    const int seg = (l & 3) * 8;

    const __bf16* Ab  = (const __bf16*)g.A + aoff + (size_t)(brow + sar) * g.lda + seg + k_begin;
    const float*  Af  = (const float*)g.A + aoff + (size_t)(brow + sar) * g.lda;  // abs-col
    const __bf16* Bg0 = g.BT + (size_t)(bcol + sbr) * g.ldbt + seg + k_begin;
    const __bf16* Bg1 = Bg0 + (size_t)16 * g.ldbt;
    const int kcl = g.Kvalid - 8;   // clamp: reads stay valid; B zero-pad kills products

    f32x4 acc[2][4] = {};
    const int fr = l & 15, fk = (l >> 4) * 8;
    const int wr = (w >> 1) * 32, wc = (w & 1) * 64;
    const int kmax = (nt - 1) * 32;

#define ISSUE_B(slot)                                                      \
    {                                                                      \
        const int _s = (slot);                                             \
        const int _k = (_s * 32 < kmax) ? _s * 32 : kmax;                  \
        const int _b = _s & 3;                                             \
        gload16(Bg0 + _k, &Bs[_b][w * 32][0]);                             \
        gload16(Bg1 + _k, &Bs[_b][w * 32 + 16][0]);                        \
    }
#define ISSUE_AB(slot)                                                     \
    {                                                                      \
        const int _s = (slot);                                             \
        const int _k = (_s * 32 < kmax) ? _s * 32 : kmax;                  \
        const int _b = _s & 3;                                             \
        gload16(Ab + _k,  &As[_b][w * 16][0]);                             \
        gload16(Bg0 + _k, &Bs[_b][w * 32][0]);                             \
        gload16(Bg1 + _k, &Bs[_b][w * 32 + 16][0]);                        \
    }

    if constexpr (AFP32) {
        f32x4 r0a, r0b, r1a, r1b, r2a, r2b, r3a, r3b;

        auto aload = [&](int slot, f32x4& ra, f32x4& rb) {
            int c = k_begin + slot * 32 + seg;
            c = c < kcl ? c : kcl;
            ra = *(const f32x4*)(Af + c);
            rb = *(const f32x4*)(Af + c + 4);
        };
        auto awrite = [&](int bufi, f32x4& ra, f32x4& rb) {
            __bf16 o[8];
#pragma unroll
            for (int z = 0; z < 4; ++z) { o[z] = (__bf16)ra[z]; o[4 + z] = (__bf16)rb[z]; }
            *(bf16x8*)&As[bufi][sar][seg] = *(bf16x8*)o;
        };
        auto astep = [&](int t, f32x4& wa, f32x4& wb, f32x4& la, f32x4& lb) {
            asm volatile("s_waitcnt vmcnt(4)" ::: "memory");
            asm volatile("s_waitcnt lgkmcnt(0)" ::: "memory");
            __builtin_amdgcn_s_barrier();
            const int bi = t & 3;
            bf16x8 a[2], b[4];
#pragma unroll
            for (int m = 0; m < 2; ++m) a[m] = *(const bf16x8*)&As[bi][wr + m * 16 + fr][fk];
#pragma unroll
            for (int n = 0; n < 4; ++n) b[n] = *(const bf16x8*)&Bs[bi][wc + n * 16 + fr][fk];
            awrite((t + 1) & 3, wa, wb);       // regs loaded 2 steps ago (vmcnt(4)-safe)
            aload(t + 3, la, lb);              // 2 reg gloads
            ISSUE_B(t + 2)                     // 2 gload_lds
#pragma unroll
            for (int m = 0; m < 2; ++m)
#pragma unroll
                for (int n = 0; n < 4; ++n)
                    acc[m][n] = __builtin_amdgcn_mfma_f32_16x16x32_bf16(a[m], b[n], acc[m][n], 0, 0, 0);
        };

        // prologue: A(0) staged; queue = [A1 A1 B0 B0 A2 A2 B1 B1]
        aload(0, r0a, r0b);
        asm volatile("s_waitcnt vmcnt(0)" ::: "memory");
        awrite(0, r0a, r0b);
        aload(1, r1a, r1b);
        ISSUE_B(0)
        aload(2, r2a, r2b);
        ISSUE_B(1)

        for (int t = 0; t < nt; t += 4) {      // nt % 4 == 0 for AFP32 shapes
            astep(t,     r1a, r1b, r3a, r3b);
            astep(t + 1, r2a, r2b, r0a, r0b);
            astep(t + 2, r3a, r3b, r1a, r1b);
            astep(t + 3, r0a, r0b, r2a, r2b);
        }
    } else {
        ISSUE_AB(0) ISSUE_AB(1) ISSUE_AB(2)
        for (int t = 0; t < nt; ++t) {
            asm volatile("s_waitcnt vmcnt(6)" ::: "memory");
            asm volatile("s_waitcnt lgkmcnt(0)" ::: "memory");
            __builtin_amdgcn_s_barrier();
            const int bi = t & 3;
            bf16x8 a[2], b[4];
#pragma unroll
            for (int m = 0; m < 2; ++m) a[m] = *(const bf16x8*)&As[bi][wr + m * 16 + fr][fk];
#pragma unroll
            for (int n = 0; n < 4; ++n) b[n] = *(const bf16x8*)&Bs[bi][wc + n * 16 + fr][fk];
            ISSUE_AB(t + 3)
#pragma unroll
            for (int m = 0; m < 2; ++m)
#pragma unroll
                for (int n = 0; n < 4; ++n)
                    acc[m][n] = __builtin_amdgcn_mfma_f32_16x16x32_bf16(a[m], b[n], acc[m][n], 0, 0, 0);
        }
    }
#undef ISSUE_B
#undef ISSUE_AB

    // epilogue: raw fp32 store. C/D: col=lane&15, row=(lane>>4)*4+reg
    const int fq = (l >> 4) * 4;
#pragma unroll
    for (int m = 0; m < 2; ++m)
#pragma unroll
        for (int n = 0; n < 4; ++n)
#pragma unroll
            for (int r = 0; r < 4; ++r) {
                int row = brow + wr + m * 16 + fq + r;
                int col = bcol + wc + n * 16 + fr;
                C[(size_t)row * g.ldc + col] = acc[m][n][r];
            }
}

// ---------------- prep: LDS-tiled weight transposes (coalesced both sides) --
// 896 blocks: WT 256 | WcatT 128 | cdT 64 | cwT 64 | kernT 192 | rkernT 192
__global__ __launch_bounds__(256) void prep_wT(
    const float* __restrict__ ew1, const float* __restrict__ ew2,
    const float* __restrict__ w12, const float* __restrict__ u12,
    const float* __restrict__ v12, const float* __restrict__ w21,
    const float* __restrict__ u21, const float* __restrict__ v21,
    const float* __restrict__ cd_w, const float* __restrict__ cw_w,
    const float* __restrict__ kern, const float* __restrict__ rkern,
    __bf16* __restrict__ WT, __bf16* __restrict__ WcatT,
    __bf16* __restrict__ cdT, __bf16* __restrict__ cwT,
    __bf16* __restrict__ kernT, __bf16* __restrict__ rkernT)
{
    __shared__ float tile[64][65];
    const int b = blockIdx.x, tid = threadIdx.x;
    const int tr = tid >> 6, tc = tid & 63;

    const float* src = nullptr;
    int ldsrc = 0, srow0 = 0, scol0 = 0, kvalid = 1 << 30;
    __bf16* dst; int ldd, n0, k0;
    bool zero = false;

    if (b < 256) {                         // WT: out 512 x 2048
        int q = b; n0 = (q >> 5) * 64; k0 = (q & 31) * 64;
        dst = WT; ldd = 2048; kvalid = 2000; ldsrc = 256; srow0 = k0;
        if (n0 < 256) { src = ew1; scol0 = n0; } else { src = ew2; scol0 = n0 - 256; }
    } else if (b < 384) {                  // WcatT: out 1024 x 512
        int q = b - 256; n0 = (q >> 3) * 64; k0 = (q & 7) * 64;
        dst = WcatT; ldd = 512; ldsrc = 256; srow0 = k0 & 255; scol0 = n0 & 255;
        int qn = n0 >> 8; bool khi = k0 >= 256;
        if (qn == 0)      src = khi ? u12 : w12;
        else if (qn == 1) src = khi ? w21 : u21;
        else if (qn == 2) { if (khi) src = v12; else zero = true; }
        else              { if (khi) zero = true; else src = v21; }
    } else if (b < 448) {                  // cdT: out 512 x 512
        int q = b - 384; n0 = (q >> 3) * 64; k0 = (q & 7) * 64;
        src = cd_w; ldsrc = 512; srow0 = k0; scol0 = n0; dst = cdT; ldd = 512;
    } else if (b < 512) {                  // cwT
        int q = b - 448; n0 = (q >> 3) * 64; k0 = (q & 7) * 64;
        src = cw_w; ldsrc = 512; srow0 = k0; scol0 = n0; dst = cwT; ldd = 512;
    } else if (b < 704) {                  // kernT: out 1536 x 512
        int q = b - 512; n0 = (q >> 3) * 64; k0 = (q & 7) * 64;
        src = kern; ldsrc = 1536; srow0 = k0; scol0 = n0; dst = kernT; ldd = 512;
    } else {                               // rkernT
        int q = b - 704; n0 = (q >> 3) * 64; k0 = (q & 7) * 64;
        src = rkern; ldsrc = 1536; srow0 = k0; scol0 = n0; dst = rkernT; ldd = 512;
    }

#pragma unroll
    for (int p = 0; p < 16; ++p) {
        int kr = p * 4 + tr;
        float v = 0.f;
        if (!zero && (srow0 + kr) < kvalid)
            v = src[(size_t)(srow0 + kr) * ldsrc + scol0 + tc];
        tile[kr][tc] = v;
    }
    __syncthreads();
#pragma unroll
    for (int p = 0; p < 16; ++p) {
        int nr = p * 4 + tr;
        dst[(size_t)(n0 + nr) * ldd + k0 + tc] = (__bf16)tile[tc][nr];
    }
}

// ---------------- R-A: E = bf16(sum P12), cro = bf16(tanh(P4 + cd_b)) -------
__global__ __launch_bounds__(256) void reduce_A(
    const float* __restrict__ P12, const float* __restrict__ P4,
    const float* __restrict__ cd_b,
    __bf16* __restrict__ E, __bf16* __restrict__ cro)
{
    int b = blockIdx.x;
    int i = (((b & 2047) * 256) + threadIdx.x) * 4;
    if (b < 2048) {
        f32x4 p0 = *(const f32x4*)(P12 + i);
        f32x4 p1 = *(const f32x4*)(P12 + (1 << 21) + i);
        __bf16 o[4];
#pragma unroll
        for (int j = 0; j < 4; ++j) o[j] = (__bf16)(p0[j] + p1[j]);
        *(bf16x4*)&E[i] = *(bf16x4*)o;
    } else {
        f32x4 p0 = *(const f32x4*)(P4 + i);
        int c = i & 511;
        __bf16 o[4];
#pragma unroll
        for (int j = 0; j < 4; ++j) o[j] = (__bf16)tanhf(p0[j] + cd_b[c + j]);
        *(bf16x4*)&cro[i] = *(bf16x4*)o;
    }
}

// ---------------- fuse1: attention softmax + x + crohis_new, and hprev ------
__global__ __launch_bounds__(256) void fuse1(
    const float* __restrict__ T, const __bf16* __restrict__ E,
    const float* __restrict__ crohis,
    const float* __restrict__ P5,
    const float* __restrict__ h_tm1, const float* __restrict__ cw_b,
    __bf16* __restrict__ x, float* __restrict__ cro_out,
    float* __restrict__ hprev, __bf16* __restrict__ hprev_bf)
{
    __shared__ float s4[4];
    int b = blockIdx.x;
    int j = threadIdx.x;
    if (b < 4096) {
        const float* t = T + (size_t)b * 1024;
        float s12 = tanhf(t[j])       * t[512 + j];
        float s21 = tanhf(t[256 + j]) * t[768 + j];
        float v = s12;
#pragma unroll
        for (int o = 32; o >= 1; o >>= 1) v = fmaxf(v, __shfl_xor(v, o, 64));
        __syncthreads(); if ((j & 63) == 0) s4[j >> 6] = v; __syncthreads();
        float m12 = fmaxf(fmaxf(s4[0], s4[1]), fmaxf(s4[2], s4[3]));
        float e12 = expf(s12 - m12);
        v = e12;
#pragma unroll
        for (int o = 32; o >= 1; o >>= 1) v += __shfl_xor(v, o, 64);
        __syncthreads(); if ((j & 63) == 0) s4[j >> 6] = v; __syncthreads();
        float sum12 = s4[0] + s4[1] + s4[2] + s4[3];
        v = s21;
#pragma unroll
        for (int o = 32; o >= 1; o >>= 1) v = fmaxf(v, __shfl_xor(v, o, 64));
        __syncthreads(); if ((j & 63) == 0) s4[j >> 6] = v; __syncthreads();
        float m21 = fmaxf(fmaxf(s4[0], s4[1]), fmaxf(s4[2], s4[3]));
        float e21 = expf(s21 - m21);
        v = e21;
#pragma unroll
        for (int o = 32; o >= 1; o >>= 1) v += __shfl_xor(v, o, 64);
        __syncthreads(); if ((j & 63) == 0) s4[j >> 6] = v; __syncthreads();
        float sum21 = s4[0] + s4[1] + s4[2] + s4[3];

        size_t b0 = (size_t)b * 512 + j, b1 = b0 + 256;
        float x1 = (float)E[b0] * (e12 / sum12);
        float x2 = (float)E[b1] * (e21 / sum21);
        x[b0] = (__bf16)x1;
        x[b1] = (__bf16)x2;
        cro_out[b0] = TAU_F * crohis[b0] + (1.f - TAU_F) * x1;
        cro_out[b1] = TAU_F * crohis[b1] + (1.f - TAU_F) * x2;
    } else {
        int i = ((b - 4096) * 256 + j) * 4;
        f32x4 p = *(const f32x4*)(P5 + i);
        f32x4 ht = *(const f32x4*)(h_tm1 + i);
        int c = i & 511;
        f32x4 o; __bf16 ob[4];
#pragma unroll
        for (int q = 0; q < 4; ++q) {
            float hv = ht[q] + tanhf(p[q] + cw_b[c + q]);
            o[q] = hv; ob[q] = (__bf16)hv;
        }
        *(f32x4*)(hprev + i) = o;
        *(bf16x4*)&hprev_bf[i] = *(bf16x4*)ob;
    }
}

// ---------------- gates: rh = sigmoid(mx_r + bias_r + mi_r) * hprev ----------
__global__ __launch_bounds__(256) void gates_k(
    const float* __restrict__ mx, const float* __restrict__ mi2,
    const float* __restrict__ hprev, const float* __restrict__ bias,
    __bf16* __restrict__ rh)
{
    int i = (blockIdx.x * 256 + threadIdx.x) * 4;
    int row = i >> 9, c = i & 511;
    f32x4 a  = *(const f32x4*)(mx + (size_t)row * 1536 + 512 + c);
    f32x4 m  = *(const f32x4*)(mi2 + (size_t)row * 1024 + 512 + c);
    f32x4 hp = *(const f32x4*)(hprev + i);
    f32x4 bb = *(const f32x4*)(bias + 512 + c);
    __bf16 o[4];
#pragma unroll
    for (int q = 0; q < 4; ++q) {
        float r = 1.f / (1.f + expf(-(a[q] + bb[q] + m[q])));
        o[q] = (__bf16)(r * hp[q]);
    }
    *(bf16x4*)&rh[i] = *(bf16x4*)o;
}

// ---------------- final: h ---------------------------------------------------
__global__ __launch_bounds__(256) void final_k(
    const float* __restrict__ mx, const float* __restrict__ mi2,
    const float* __restrict__ P8a, const float* __restrict__ P8b,
    const float* __restrict__ hprev, const float* __restrict__ bias,
    float* __restrict__ h)
{
    int i = (blockIdx.x * 256 + threadIdx.x) * 4;
    int row = i >> 9, c = i & 511;
    f32x4 xz = *(const f32x4*)(mx + (size_t)row * 1536 + c);
    f32x4 xh = *(const f32x4*)(mx + (size_t)row * 1536 + 1024 + c);
    f32x4 mz = *(const f32x4*)(mi2 + (size_t)row * 1024 + c);
    f32x4 p0 = *(const f32x4*)(P8a + i);
    f32x4 p1 = *(const f32x4*)(P8b + i);
    f32x4 hp = *(const f32x4*)(hprev + i);
    f32x4 bz = *(const f32x4*)(bias + c);
    f32x4 bh = *(const f32x4*)(bias + 1024 + c);
    f32x4 o;
#pragma unroll
    for (int q = 0; q < 4; ++q) {
        float z = 1.f / (1.f + expf(-(xz[q] + bz[q] + mz[q])));
        float hh = tanhf(xh[q] + bh[q] + p0[q] + p1[q]);
        o[q] = z * hp[q] + (1.f - z) * hh;
    }
    *(f32x4*)(h + i) = o;
}

// ---------------- launch -----------------------------------------------------
extern "C" void kernel_launch(void* const* d_in, const int* in_sizes, int n_in,
                              void* d_out, int out_size, void* d_ws, size_t ws_size,
                              hipStream_t stream)
{
    (void)in_sizes; (void)n_in; (void)out_size; (void)ws_size;

    const float* inputs = (const float*)d_in[0];
    const float* h_tm1  = (const float*)d_in[1];
    const float* crohis = (const float*)d_in[2];
    const float* ew1    = (const float*)d_in[3];
    const float* ew2    = (const float*)d_in[4];
    const float* ca12w  = (const float*)d_in[5];
    const float* ca12u  = (const float*)d_in[6];
    const float* ca12v  = (const float*)d_in[7];
    const float* ca21w  = (const float*)d_in[8];
    const float* ca21u  = (const float*)d_in[9];
    const float* ca21v  = (const float*)d_in[10];
    const float* cw_w   = (const float*)d_in[11];
    const float* cw_b   = (const float*)d_in[12];
    const float* cd_w   = (const float*)d_in[13];
    const float* cd_b   = (const float*)d_in[14];
    const float* kern   = (const float*)d_in[15];
    const float* rkern  = (const float*)d_in[16];
    const float* bias   = (const float*)d_in[17];

    char* ws = (char*)d_ws;
    const size_t MB = 1 << 20;
    float*  P12      = (float*)(ws + 0);          // 16MB [A]
    float*  P4       = (float*)(ws + 16 * MB);    // 8MB  [A]
    __bf16* E        = (__bf16*)(ws + 32 * MB);   // 4MB  [redA..fuse1]
    __bf16* cro_bf   = (__bf16*)(ws + 36 * MB);   // 4MB  [redA..B]
    float*  T        = (float*)(ws + 0);          // 16MB [B..fuse1]
    float*  P5       = (float*)(ws + 16 * MB);    // 8MB  [B..fuse1]
    __bf16* x        = (__bf16*)(ws + 40 * MB);   // 4MB  [fuse1..C]
    float*  hprev    = (float*)(ws + 24 * MB);    // 8MB  [fuse1..final]
    __bf16* hprev_bf = (__bf16*)(ws + 64 * MB);   // 4MB  [fuse1..C]
    float*  mx       = (float*)(ws + 0);          // 24MB [C..final]
    float*  mi2      = (float*)(ws + 44 * MB);    // 16MB [C..final]
    __bf16* rh       = (__bf16*)(ws + 32 * MB);   // 4MB  [gates..G8] (over E)
    float*  P8       = (float*)(ws + 36 * MB);    // s0 @36-44 (over cro_bf/x)
    float*  P8b      = (float*)(ws + 60 * MB);    // s1 @60-68 (over hprev_bf)
    __bf16* WT       = (__bf16*)(ws + 68 * MB);   // 2MB
    __bf16* WcatT    = (__bf16*)(ws + 70 * MB);   // 1MB
    __bf16* cdT      = (__bf16*)(ws + 71 * MB);   // 0.5MB
    __bf16* cwT      = (__bf16*)(ws + 71 * MB + 512 * 1024);
    __bf16* kernT    = (__bf16*)(ws + 72 * MB);   // 1.5MB
    __bf16* rkernT   = (__bf16*)(ws + 73 * MB + 512 * 1024);  // ends 75MB

    float* h_out   = (float*)d_out;
    float* cro_out = (float*)d_out + 2 * 1048576;

    const int BIG = 1 << 30;

    prep_wT<<<896, 256, 0, stream>>>(ew1, ew2, ca12w, ca12u, ca12v, ca21w,
                                     ca21u, ca21v, cd_w, cw_w, kern, rkern,
                                     WT, WcatT, cdT, cwT, kernT, rkernT);

    // Phase A (AFP32): G12 (split-K=2, fp32 inputs) + G4 (fp32 crohis) [nwg=768]
    SubGemm gA1 = { inputs, 4000, 2000, WT,  2048, P12, 512, 1ll << 21, 1024, 4, 2, 2000 };
    SubGemm gA2 = { crohis,  512,  512, cdT,  512, P4,  512, 0,          512, 4, BIG, 0 };
    gemm_dual<true><<<dim3(12, 64), 256, 0, stream>>>(gA1, gA2, 8);

    reduce_A<<<4096, 256, 0, stream>>>(P12, P4, cd_b, E, cro_bf);

    // Phase B: G3 + G5 (bf16)                         [nwg=768]
    SubGemm gB1 = { E,      512, 512, WcatT, 512, T,  1024, 0, 512, 8, BIG, 0 };
    SubGemm gB2 = { cro_bf, 512, 512, cwT,   512, P5, 512,  0, 512, 4, BIG, 0 };
    gemm_dual<false><<<dim3(12, 64), 256, 0, stream>>>(gB1, gB2, 8);

    fuse1<<<6144, 256, 0, stream>>>(T, E, crohis, P5, h_tm1, cw_b,
                                    x, cro_out, hprev, hprev_bf);

    // Phase C: G6 (mx) + G7 (mi2)                      [nwg=1280]
    SubGemm gC1 = { x,        512, 512, kernT,  512, mx,  1536, 0, 512, 12, BIG, 0 };
    SubGemm gC2 = { hprev_bf, 512, 512, rkernT, 512, mi2, 1024, 0, 512, 8,  BIG, 0 };
    gemm_dual<false><<<dim3(20, 64), 256, 0, stream>>>(gC1, gC2, 12);

    gates_k<<<2048, 256, 0, stream>>>(mx, mi2, hprev, bias, rh);

    // G8: split-K=2 (slices @36MB, @60MB)              [nwg=512]
    SubGemm gG = { rh, 512, 512, rkernT + (size_t)1024 * 512, 512, P8, 512, 6ll << 20, 256, 4, BIG, 0 };
    gemm_dual<false><<<dim3(8, 64), 256, 0, stream>>>(gG, gG, 8);

    final_k<<<2048, 256, 0, stream>>>(mx, mi2, P8, P8b, hprev, bias, h_out);
}